// Round 3
// baseline (1177.960 us; speedup 1.0000x reference)
//
#include <hip/hip_runtime.h>

#define NN 100000
#define NE 1600000
#define NPART 391          // ceil(NN/256) node partitions of 256 nodes
#define CAP 5120           // edges capacity per partition (mean 4096, sigma ~64)

// ---- edge partitioning: part[p] collects packed (local_dst<<17 | src) ------
__global__ __launch_bounds__(256) void part_kernel(
    const int* __restrict__ src, const int* __restrict__ dst,
    int* __restrict__ cur, unsigned* __restrict__ part)
{
    int e = blockIdx.x * 256 + threadIdx.x;
    if (e >= NE) return;
    int s = src[e], d = dst[e];
    int p = d >> 8;
    int pos = atomicAdd(&cur[p], 1);
    if (pos < CAP)
        part[(size_t)p * CAP + pos] = ((unsigned)(d & 255) << 17) | (unsigned)s;
}

// ---- per-partition aggregation in LDS: A[n][:] = sum_{e:dst=n} P[src[e]][:] -
template<int F, bool WRITE_DEG>
__global__ __launch_bounds__(256) void agg_part_kernel(
    const float* __restrict__ P, const unsigned* __restrict__ part,
    const int* __restrict__ cur, float* __restrict__ A, int* __restrict__ degi)
{
    constexpr int GL = (F == 32) ? 32 : 16;   // lanes per edge-group (== F)
    constexpr int NG = 256 / GL;              // edge-groups per block
    __shared__ float acc[256 * F];
    __shared__ int   degl[256];
    __shared__ unsigned ech[CAP];
    const int p = blockIdx.x;
    const int tid = threadIdx.x;
    const int nbase = p << 8;

    for (int i = tid; i < 256 * F; i += 256) acc[i] = 0.f;
    degl[tid] = 0;
    int cnt = cur[p]; if (cnt > CAP) cnt = CAP;
    const unsigned* pe = part + (size_t)p * CAP;
    for (int i = tid; i < cnt; i += 256) ech[i] = pe[i];   // coalesced stage
    __syncthreads();

    const int g = tid / GL, l = tid % GL;
    int e = g;
    // 8-deep batched gathers for memory-level parallelism
    for (; e + NG * 7 < cnt; e += NG * 8) {
        unsigned ev[8]; float v[8];
#pragma unroll
        for (int u = 0; u < 8; ++u) ev[u] = ech[e + NG * u];
#pragma unroll
        for (int u = 0; u < 8; ++u)
            v[u] = P[(size_t)(ev[u] & 0x1FFFFu) * F + l];
#pragma unroll
        for (int u = 0; u < 8; ++u) {
            unsigned ld = ev[u] >> 17;
            atomicAdd(&acc[ld * F + l], v[u]);
            if (WRITE_DEG && l == 0) atomicAdd(&degl[ld], 1);
        }
    }
    for (; e < cnt; e += NG) {
        unsigned ev = ech[e];
        float v = P[(size_t)(ev & 0x1FFFFu) * F + l];
        unsigned ld = ev >> 17;
        atomicAdd(&acc[ld * F + l], v);
        if (WRITE_DEG && l == 0) atomicAdd(&degl[ld], 1);
    }
    __syncthreads();

    const int nmax = (NN - nbase < 256) ? (NN - nbase) : 256;
    for (int i = tid; i < nmax * F; i += 256)
        A[(size_t)nbase * F + i] = acc[i];
    if (WRITE_DEG)
        for (int i = tid; i < nmax; i += 256) degi[nbase + i] = degl[i];
}

// ---- dense projection (+ fused mean/bias epilogue) --------------------------
// Y[n][j] = dot(X[n], W[:,j])  (+ bias[j] + agg[n][j]/max(deg[n],1) if FUSE)
template<int IN_F, int OUT_F, bool FUSE>
__global__ __launch_bounds__(256) void proj_kernel(
    const float* __restrict__ X, const float* __restrict__ W,
    const float* __restrict__ bias, const float* __restrict__ agg,
    const int* __restrict__ cnt, float* __restrict__ Y)
{
    constexpr int NPB = 256 / OUT_F;           // nodes per block
    __shared__ float Wl[IN_F * OUT_F];
    __shared__ float Xl[NPB][IN_F];
    const int tid = threadIdx.x;
    for (int i = tid; i < IN_F * OUT_F; i += 256) Wl[i] = W[i];
    const int nbase = blockIdx.x * NPB;
    for (int i = tid; i < NPB * IN_F; i += 256) {
        int ln = i / IN_F, k = i % IN_F;
        int n = nbase + ln;
        Xl[ln][k] = (n < NN) ? X[(size_t)n * IN_F + k] : 0.f;
    }
    __syncthreads();
    const int j  = tid % OUT_F;
    const int ln = tid / OUT_F;
    const int n  = nbase + ln;
    if (n >= NN) return;
    float acc = 0.f;
#pragma unroll
    for (int k = 0; k < IN_F; ++k) acc += Xl[ln][k] * Wl[k * OUT_F + j];
    if (FUSE) {
        float d = (float)cnt[n];
        if (d < 1.f) d = 1.f;
        acc += bias[j] + agg[(size_t)n * OUT_F + j] / d;
    }
    Y[(size_t)n * OUT_F + j] = acc;
}

// ---- launch -----------------------------------------------------------------
extern "C" void kernel_launch(void* const* d_in, const int* in_sizes, int n_in,
                              void* d_out, int out_size, void* d_ws, size_t ws_size,
                              hipStream_t stream)
{
    const float* x   = (const float*)d_in[0];
    const int*   src = (const int*)d_in[1];
    const int*   dst = (const int*)d_in[2];
    const float* Ws1 = (const float*)d_in[3];
    const float* Wn1 = (const float*)d_in[4];
    const float* b1  = (const float*)d_in[5];
    const float* Ws2 = (const float*)d_in[6];
    const float* Wn2 = (const float*)d_in[7];
    const float* b2  = (const float*)d_in[8];
    float* out = (float*)d_out;

    char* ws = (char*)d_ws;
    int*      cur  = (int*)(ws);                         // NPART ints
    int*      degi = (int*)(ws + (512u << 10));          // NN ints (400 KB)
    unsigned* part = (unsigned*)(ws + (1u << 20));       // NPART*CAP u32 = 8 MB
    float*    bufA = (float*)(ws + (9u << 20));          // 12.8 MB: P1, then H1
    float*    bufB = (float*)(ws + (22u << 20));         // 12.8 MB: A1, then P2|A2
    float*    P2   = bufB;                               // NN*16
    float*    A2   = bufB + (size_t)NN * 16;             // NN*16

    // ---- build partitioned edge list (shared by both layers) ----
    hipMemsetAsync(cur, 0, NPART * sizeof(int), stream);
    part_kernel<<<(NE + 255) / 256, 256, 0, stream>>>(src, dst, cur, part);

    // ---- layer 1 ----
    proj_kernel<64, 32, false><<<(NN + 7) / 8, 256, 0, stream>>>(
        x, Wn1, nullptr, nullptr, nullptr, bufA);          // P1 = x @ Wn1
    agg_part_kernel<32, true><<<NPART, 256, 0, stream>>>(
        bufA, part, cur, bufB, degi);                      // A1 = sum P1[src], deg
    proj_kernel<64, 32, true><<<(NN + 7) / 8, 256, 0, stream>>>(
        x, Ws1, b1, bufB, degi, bufA);                     // H1 = x@Ws1+b1+A1/deg

    // ---- layer 2 ----
    proj_kernel<32, 16, false><<<(NN + 15) / 16, 256, 0, stream>>>(
        bufA, Wn2, nullptr, nullptr, nullptr, P2);         // P2 = H1 @ Wn2
    agg_part_kernel<16, false><<<NPART, 256, 0, stream>>>(
        P2, part, cur, A2, nullptr);                       // A2 = sum P2[src]
    proj_kernel<32, 16, true><<<(NN + 15) / 16, 256, 0, stream>>>(
        bufA, Ws2, b2, A2, degi, out);                     // out = H1@Ws2+b2+A2/deg
}

// Round 4
// 186.869 us; speedup vs baseline: 6.3037x; 6.3037x over previous
//
#include <hip/hip_runtime.h>

#define NN 100000
#define NE 1600000
#define NPART 391                 // ceil(NN/256) buckets of 256 nodes
#define CAP 4608                  // per-bucket capacity (mean 4096, sigma 64)
#define CHUNK 8192
#define NCHUNK ((NE + CHUNK - 1) / CHUNK)   // 196

// ---- phase A: bin edges by dst>>8, block-bulk reservation (depth<=NCHUNK) ---
__global__ __launch_bounds__(256) void bin_kernel(
    const int* __restrict__ src, const int* __restrict__ dst,
    int* __restrict__ gcur, unsigned* __restrict__ bucket)
{
    __shared__ int hist[NPART];
    __shared__ int cur[NPART];
    const int tid = threadIdx.x;
    const int e0 = blockIdx.x * CHUNK;
    const int e1 = (e0 + CHUNK < NE) ? e0 + CHUNK : NE;
    for (int i = tid; i < NPART; i += 256) hist[i] = 0;
    __syncthreads();
    for (int e = e0 + tid; e < e1; e += 256)
        atomicAdd(&hist[dst[e] >> 8], 1);
    __syncthreads();
    for (int b = tid; b < NPART; b += 256) {
        int h = hist[b];
        cur[b] = h ? atomicAdd(&gcur[b], h) : 0;   // one global atomic per (block,bucket)
    }
    __syncthreads();
    for (int e = e0 + tid; e < e1; e += 256) {
        int d = dst[e];
        int p = d >> 8;
        int pos = atomicAdd(&cur[p], 1);           // LDS cursor
        if (pos < CAP)
            bucket[(size_t)p * CAP + pos] = ((unsigned)(d & 255) << 17) | (unsigned)src[e];
    }
}

// ---- exclusive scan of bucket counts -> bucket bases ------------------------
__global__ __launch_bounds__(512) void bscan_kernel(const int* __restrict__ gcur,
                                                    int* __restrict__ bbase)
{
    __shared__ int s[512];
    const int tid = threadIdx.x;
    int c = (tid < NPART) ? gcur[tid] : 0;
    int v = (c < CAP) ? c : CAP;
    s[tid] = v;
    __syncthreads();
    for (int d = 1; d < 512; d <<= 1) {
        int t = (tid >= d) ? s[tid - d] : 0;
        __syncthreads();
        s[tid] += t;
        __syncthreads();
    }
    if (tid < NPART) bbase[tid] = s[tid] - v;
}

// ---- phase B: per-bucket CSR fill, window-local writes ----------------------
// Produces off[n] = END of node n's edge range (R2 post-fill semantics),
// degi[n] = in-degree, esrc[] = src ids grouped by dst.
__global__ __launch_bounds__(256) void csrfill_kernel(
    const unsigned* __restrict__ bucket, const int* __restrict__ gcur,
    const int* __restrict__ bbase, int* __restrict__ off,
    int* __restrict__ degi, int* __restrict__ esrc)
{
    __shared__ unsigned ech[CAP];
    __shared__ int cntl[256];
    __shared__ int scn[256];
    __shared__ int curl[256];
    const int p = blockIdx.x, tid = threadIdx.x;
    const int nbase = p << 8;
    const int nmax = (NN - nbase < 256) ? (NN - nbase) : 256;
    int cnt = gcur[p]; if (cnt > CAP) cnt = CAP;
    const int base = bbase[p];
    cntl[tid] = 0;
    const unsigned* bp = bucket + (size_t)p * CAP;
    for (int i = tid; i < cnt; i += 256) ech[i] = bp[i];        // coalesced stage
    __syncthreads();
    for (int i = tid; i < cnt; i += 256) atomicAdd(&cntl[ech[i] >> 17], 1);
    __syncthreads();
    const int v = cntl[tid];
    scn[tid] = v;
    __syncthreads();
    for (int d = 1; d < 256; d <<= 1) {
        int t = (tid >= d) ? scn[tid - d] : 0;
        __syncthreads();
        scn[tid] += t;
        __syncthreads();
    }
    if (tid < nmax) {
        off[nbase + tid]  = base + scn[tid];    // end-of-node
        degi[nbase + tid] = v;
    }
    curl[tid] = base + scn[tid] - v;            // start cursor
    __syncthreads();
    for (int i = tid; i < cnt; i += 256) {
        unsigned ev = ech[i];
        int pos = atomicAdd(&curl[ev >> 17], 1);
        esrc[pos] = (int)(ev & 0x1FFFFu);       // contiguous 16KB window per block
    }
}

// ---- gather-aggregate: A[n][:] = sum_{e in bucket(n)} P[esrc[e]][:] ---------
template<int F>
__global__ __launch_bounds__(256) void agg_kernel(const float* __restrict__ P,
                                                  const int* __restrict__ esrc,
                                                  const int* __restrict__ off,
                                                  float* __restrict__ A) {
    constexpr int Q = F / 4;
    int t = blockIdx.x * 256 + threadIdx.x;
    int n = t / Q, q = t % Q;
    if (n >= NN) return;
    int e0 = (n > 0) ? off[n - 1] : 0;
    int e1 = off[n];
    float4 a0 = {0.f, 0.f, 0.f, 0.f}, a1 = {0.f, 0.f, 0.f, 0.f};
    int e = e0;
    for (; e + 1 < e1; e += 2) {
        int s0 = esrc[e], s1 = esrc[e + 1];
        const float4 v0 = *reinterpret_cast<const float4*>(P + (size_t)s0 * F + q * 4);
        const float4 v1 = *reinterpret_cast<const float4*>(P + (size_t)s1 * F + q * 4);
        a0.x += v0.x; a0.y += v0.y; a0.z += v0.z; a0.w += v0.w;
        a1.x += v1.x; a1.y += v1.y; a1.z += v1.z; a1.w += v1.w;
    }
    if (e < e1) {
        int s0 = esrc[e];
        const float4 v0 = *reinterpret_cast<const float4*>(P + (size_t)s0 * F + q * 4);
        a0.x += v0.x; a0.y += v0.y; a0.z += v0.z; a0.w += v0.w;
    }
    float4 r;
    r.x = a0.x + a1.x; r.y = a0.y + a1.y; r.z = a0.z + a1.z; r.w = a0.w + a1.w;
    *reinterpret_cast<float4*>(A + (size_t)n * F + q * 4) = r;
}

// ---- dense projection (+ fused mean/bias epilogue) --------------------------
template<int IN_F, int OUT_F, bool FUSE>
__global__ __launch_bounds__(256) void proj_kernel(
    const float* __restrict__ X, const float* __restrict__ W,
    const float* __restrict__ bias, const float* __restrict__ agg,
    const int* __restrict__ cnt, float* __restrict__ Y)
{
    constexpr int NPB = 256 / OUT_F;
    __shared__ float Wl[IN_F * OUT_F];
    __shared__ float Xl[NPB][IN_F];
    const int tid = threadIdx.x;
    for (int i = tid; i < IN_F * OUT_F; i += 256) Wl[i] = W[i];
    const int nbase = blockIdx.x * NPB;
    for (int i = tid; i < NPB * IN_F; i += 256) {
        int ln = i / IN_F, k = i % IN_F;
        int n = nbase + ln;
        Xl[ln][k] = (n < NN) ? X[(size_t)n * IN_F + k] : 0.f;
    }
    __syncthreads();
    const int j  = tid % OUT_F;
    const int ln = tid / OUT_F;
    const int n  = nbase + ln;
    if (n >= NN) return;
    float acc = 0.f;
#pragma unroll
    for (int k = 0; k < IN_F; ++k) acc += Xl[ln][k] * Wl[k * OUT_F + j];
    if (FUSE) {
        float d = (float)cnt[n];
        if (d < 1.f) d = 1.f;
        acc += bias[j] + agg[(size_t)n * OUT_F + j] / d;
    }
    Y[(size_t)n * OUT_F + j] = acc;
}

// ---- launch -----------------------------------------------------------------
extern "C" void kernel_launch(void* const* d_in, const int* in_sizes, int n_in,
                              void* d_out, int out_size, void* d_ws, size_t ws_size,
                              hipStream_t stream)
{
    const float* x   = (const float*)d_in[0];
    const int*   src = (const int*)d_in[1];
    const int*   dst = (const int*)d_in[2];
    const float* Ws1 = (const float*)d_in[3];
    const float* Wn1 = (const float*)d_in[4];
    const float* b1  = (const float*)d_in[5];
    const float* Ws2 = (const float*)d_in[6];
    const float* Wn2 = (const float*)d_in[7];
    const float* b2  = (const float*)d_in[8];
    float* out = (float*)d_out;

    char* ws = (char*)d_ws;
    int*      gcur  = (int*)(ws);                        // NPART ints
    int*      bbase = (int*)(ws + (4u << 10));           // NPART ints
    int*      degi  = (int*)(ws + (8u << 10));           // NN ints (400 KB)
    int*      off   = (int*)(ws + (416u << 10));         // NN ints (400 KB)
    unsigned* bucket= (unsigned*)(ws + (1u << 20));      // NPART*CAP u32 = 7.2 MB
    float*    bufA  = (float*)(ws + (8704u << 10));      // 12.8 MB: P1, then H1
    float*    bufB  = (float*)(ws + (22016u << 10));     // 12.8 MB: A1, then P2|A2
    float*    P2    = bufB;                              // NN*16
    float*    A2    = bufB + (size_t)NN * 16;            // NN*16
    int*      esrc  = (int*)d_out;                       // 1.6M ints = 6.4 MB, dead
                                                         // before final proj writes out

    // ---- CSR build (shared by both layers) ----
    hipMemsetAsync(gcur, 0, NPART * sizeof(int), stream);
    bin_kernel    <<<NCHUNK, 256, 0, stream>>>(src, dst, gcur, bucket);
    bscan_kernel  <<<1, 512, 0, stream>>>(gcur, bbase);
    csrfill_kernel<<<NPART, 256, 0, stream>>>(bucket, gcur, bbase, off, degi, esrc);

    // ---- layer 1 ----
    proj_kernel<64, 32, false><<<(NN + 7) / 8, 256, 0, stream>>>(
        x, Wn1, nullptr, nullptr, nullptr, bufA);          // P1 = x @ Wn1
    agg_kernel<32><<<(NN * 8 + 255) / 256, 256, 0, stream>>>(
        bufA, esrc, off, bufB);                            // A1 = sum P1[src]
    proj_kernel<64, 32, true><<<(NN + 7) / 8, 256, 0, stream>>>(
        x, Ws1, b1, bufB, degi, bufA);                     // H1 = x@Ws1+b1+A1/deg

    // ---- layer 2 ----
    proj_kernel<32, 16, false><<<(NN + 15) / 16, 256, 0, stream>>>(
        bufA, Wn2, nullptr, nullptr, nullptr, P2);         // P2 = H1 @ Wn2
    agg_kernel<16><<<(NN * 4 + 255) / 256, 256, 0, stream>>>(
        P2, esrc, off, A2);                                // A2 = sum P2[src]
    proj_kernel<32, 16, true><<<(NN + 15) / 16, 256, 0, stream>>>(
        bufA, Ws2, b2, A2, degi, out);                     // out = H1@Ws2+b2+A2/deg
}